// Round 4
// baseline (26.575 us; speedup 1.0000x reference)
//
#include <hip/hip_runtime.h>

// QuantizedEmbedding: out[t, d] = (qweight[input[t], d] - zeros[input[t]]) * scales[input[t]]
// B*S = 16384 tokens, DIM = 1024, VOCAB = 128000. Output fp32.
// Memory-bound gather: ~64 MiB read (gathered rows) + 64 MiB write -> floor ~21 us @ 6.3 TB/s.
//
// r4: grid-stride persistent blocks (2048 blocks x 256 thr, 8 tokens each) with
// metadata software pipelining: while streaming the current row's 8 KiB, issue
// the idx -> (scale, zero) dependent chain for the NEXT token. Amortizes the
// ~1000-cycle serial prologue chain to once per block (was once per token) and
// cuts block-dispatch churn 8x. Cached loads (r2: nt-loads regressed, LLC
// retention of duplicate rows matters) + nontemporal stores (write-once stream).

constexpr int DIM = 1024;

typedef int   int4v   __attribute__((ext_vector_type(4)));
typedef float float4v __attribute__((ext_vector_type(4)));

__global__ __launch_bounds__(256) void qembed_kernel(
    const int*   __restrict__ input,    // [NTOK] row indices
    const int*   __restrict__ qweight,  // [VOCAB, DIM] codes in [0,256)
    const float* __restrict__ scales,   // [VOCAB]
    const float* __restrict__ zeros,    // [VOCAB]
    float*       __restrict__ out,      // [NTOK, DIM]
    int ntok)
{
    const int t = threadIdx.x;               // 0..255: one 16B chunk of the row
    const int G = gridDim.x;
    int tok = blockIdx.x;
    if (tok >= ntok) return;

    // Prologue: metadata chain for the first token.
    int   row = input[tok];                  // block-uniform
    float sc  = scales[row];
    float zp  = zeros[row];

    for (;;) {
        // Prefetch next token's metadata chain; overlaps with this token's
        // 8 KiB of row traffic below.
        const int  ntk  = tok + G;
        const bool more = ntk < ntok;
        int   nrow = 0;
        float nsc = 0.f, nzp = 0.f;
        if (more) {
            nrow = input[ntk];
            nsc  = scales[nrow];
            nzp  = zeros[nrow];
        }

        // Stream current row: 256 threads x (16B load -> 16B nt store).
        const int4v* qrow = reinterpret_cast<const int4v*>(qweight + (size_t)row * DIM);
        float4v*     orow = reinterpret_cast<float4v*>(out + (size_t)tok * DIM);
        int4v q = qrow[t];
        float4v o;
        o.x = ((float)q.x - zp) * sc;
        o.y = ((float)q.y - zp) * sc;
        o.z = ((float)q.z - zp) * sc;
        o.w = ((float)q.w - zp) * sc;
        __builtin_nontemporal_store(o, orow + t);

        if (!more) break;
        tok = ntk; row = nrow; sc = nsc; zp = nzp;
    }
}

extern "C" void kernel_launch(void* const* d_in, const int* in_sizes, int n_in,
                              void* d_out, int out_size, void* d_ws, size_t ws_size,
                              hipStream_t stream) {
    const int*   input   = (const int*)d_in[0];    // [B*S] int32 indices
    const int*   qweight = (const int*)d_in[1];    // [VOCAB*DIM] int32 codes
    const float* scales  = (const float*)d_in[2];  // [VOCAB]
    const float* zeros   = (const float*)d_in[3];  // [VOCAB]
    float*       out     = (float*)d_out;          // [B*S*DIM] fp32

    const int ntok = in_sizes[0];                  // 16384
    const int nblocks = 2048;                      // 8 tokens per block, 8 waves/CU-slot pressure
    dim3 grid(nblocks);
    dim3 block(256);
    qembed_kernel<<<grid, block, 0, stream>>>(input, qweight, scales, zeros, out, ntok);
}

// Round 5
// 25.482 us; speedup vs baseline: 1.0429x; 1.0429x over previous
//
#include <hip/hip_runtime.h>

// QuantizedEmbedding: out[t, d] = (qweight[input[t], d] - zeros[input[t]]) * scales[input[t]]
// B*S = 16384 tokens, DIM = 1024, VOCAB = 128000. Output fp32.
//
// FINAL (= r3, measured best 25.44 us): one 256-thread block per token; each
// thread does one 16B int4 load -> dequant -> one 16B nontemporal float4 store.
// Memory-bound gather at ~5.35 TB/s effective (~85% of 6.3 TB/s D2D ceiling);
// traffic floor ~136 MB is irreducible (codes stored as int32 must be read;
// fp32 output must be written). Measured ledger:
//   r1 block/token cached+plain stores        25.75 us
//   r2 wave/token MLP=4 + nt loads/stores     27.80 us  (nt loads hurt: LLC retention lost)
//   r3 block/token cached loads + nt stores   25.44 us  <- best
//   r4 persistent blocks + pipelined metadata 26.57 us  (TLP already hides chain latency)

constexpr int DIM = 1024;

typedef int   int4v   __attribute__((ext_vector_type(4)));
typedef float float4v __attribute__((ext_vector_type(4)));

__global__ __launch_bounds__(256) void qembed_kernel(
    const int*   __restrict__ input,    // [NTOK] row indices
    const int*   __restrict__ qweight,  // [VOCAB, DIM] codes in [0,256)
    const float* __restrict__ scales,   // [VOCAB]
    const float* __restrict__ zeros,    // [VOCAB]
    float*       __restrict__ out,      // [NTOK, DIM]
    int ntok)
{
    const int tok = blockIdx.x;
    if (tok >= ntok) return;

    const int row = input[tok];              // block-uniform -> scalar load
    const float scale = scales[row];
    const float zero  = zeros[row];

    const int4v* qrow = reinterpret_cast<const int4v*>(qweight + (size_t)row * DIM);
    float4v*     orow = reinterpret_cast<float4v*>(out + (size_t)tok * DIM);

    const int t = threadIdx.x;               // 0..255 -> 256 x 16B = 4 KiB row
    int4v q = qrow[t];                       // cached load (L2/LLC retention for dup rows)
    float4v o;
    o.x = ((float)q.x - zero) * scale;
    o.y = ((float)q.y - zero) * scale;
    o.z = ((float)q.z - zero) * scale;
    o.w = ((float)q.w - zero) * scale;
    __builtin_nontemporal_store(o, orow + t);  // write-once stream, skip L2 retention
}

extern "C" void kernel_launch(void* const* d_in, const int* in_sizes, int n_in,
                              void* d_out, int out_size, void* d_ws, size_t ws_size,
                              hipStream_t stream) {
    const int*   input   = (const int*)d_in[0];    // [B*S] int32 indices
    const int*   qweight = (const int*)d_in[1];    // [VOCAB*DIM] int32 codes
    const float* scales  = (const float*)d_in[2];  // [VOCAB]
    const float* zeros   = (const float*)d_in[3];  // [VOCAB]
    float*       out     = (float*)d_out;          // [B*S*DIM] fp32

    const int ntok = in_sizes[0];                  // 16384
    dim3 grid(ntok);
    dim3 block(256);
    qembed_kernel<<<grid, block, 0, stream>>>(input, qweight, scales, zeros, out, ntok);
}